// Round 1
// baseline (195.515 us; speedup 1.0000x reference)
//
#include <hip/hip_runtime.h>
#include <math.h>

#define BS   16
#define NMAX 64
#define NA   8400
#define NCLS 80
#define TOPK 10
#define EPS7 1e-7f
#define EPS9 1e-9f

// ---------------- kernel 1: overlaps + metric per (b,n,a) ----------------
__global__ __launch_bounds__(256) void k1_compute(
    const float* __restrict__ score,    // (BS,NA,NCLS)
    const float* __restrict__ p_box,    // (BS,NA,4)
    const float* __restrict__ anchors,  // (NA,2)
    const int*   __restrict__ gt_labels,// (BS,NMAX,1)
    const float* __restrict__ gt_box,   // (BS,NMAX,4)
    const float* __restrict__ mask,     // (BS,NMAX,1)
    float* __restrict__ overlaps,       // (BS*NMAX, NA)
    float* __restrict__ metric)         // (BS*NMAX, NA)
{
    int row = blockIdx.x;              // b*NMAX + n
    int b   = row / NMAX;
    float valid = mask[row];
    const float* gb = gt_box + (size_t)row * 4;
    float gx1 = gb[0], gy1 = gb[1], gx2 = gb[2], gy2 = gb[3];
    int lbl = gt_labels[row];
    float w1 = gx2 - gx1;
    float h1 = gy2 - gy1 + EPS7;
    float at1 = atanf(w1 / h1);
    float area1 = w1 * h1;

    float* ovr = overlaps + (size_t)row * NA;
    float* mtr = metric   + (size_t)row * NA;
    const float* sc = score + (size_t)b * NA * NCLS;
    const float* pb = p_box + (size_t)b * NA * 4;

    for (int a = threadIdx.x; a < NA; a += 256) {
        float ov = 0.f, mt = 0.f;
        if (valid > 0.f) {
            float ax = anchors[a * 2], ay = anchors[a * 2 + 1];
            float dmin = fminf(fminf(ax - gx1, ay - gy1), fminf(gx2 - ax, gy2 - ay));
            if (dmin > EPS9) {
                float px1 = pb[a*4], py1 = pb[a*4+1], px2 = pb[a*4+2], py2 = pb[a*4+3];
                float w2 = px2 - px1;
                float h2 = py2 - py1 + EPS7;
                float iw = fminf(gx2, px2) - fmaxf(gx1, px1);
                float ih = fminf(gy2, py2) - fmaxf(gy1, py1);
                float inter = fmaxf(iw, 0.f) * fmaxf(ih, 0.f);
                float uni = area1 + w2 * h2 - inter + EPS7;
                float iou = inter / uni;
                float cw = fmaxf(gx2, px2) - fminf(gx1, px1);
                float ch = fmaxf(gy2, py2) - fminf(gy1, py1);
                float c2 = cw * cw + ch * ch + EPS7;
                float dx = (px1 + px2 - gx1 - gx2);
                float dy = (py1 + py2 - gy1 - gy2);
                float rho2 = (dx * dx + dy * dy) * 0.25f;
                float dat = atanf(w2 / h2) - at1;
                float v = (4.0f / (float)(M_PI * M_PI)) * dat * dat;
                float alpha = v / (v - iou + (1.0f + EPS7));
                float ciou = iou - (rho2 / c2 + v * alpha);
                ov = fmaxf(ciou, 0.f);
                float gath = sc[(size_t)a * NCLS + lbl];
                float ov2 = ov * ov;
                mt = sqrtf(gath) * ov2 * ov2 * ov2;   // gathered^0.5 * ov^6
            }
        }
        ovr[a] = ov;
        mtr[a] = mt;
    }
}

// ---------------- kernel 2: top-10 per row -> mask_pos ----------------
__global__ __launch_bounds__(256) void k2_topk(
    const float* __restrict__ metric,
    const float* __restrict__ anchors,
    const float* __restrict__ gt_box,
    const float* __restrict__ mask,
    unsigned char* __restrict__ mask_pos)   // (BS*NMAX, NA)
{
    int row = blockIdx.x;
    int tid = threadIdx.x;
    unsigned char* mp = mask_pos + (size_t)row * NA;
    for (int a = tid; a < NA; a += 256) mp[a] = 0;
    if (mask[row] <= 0.f) return;           // uniform per block

    const float* mtr = metric + (size_t)row * NA;
    // pack (value_bits << 32) | ~index : total order, value desc / index asc
    unsigned long long key[33];
#pragma unroll
    for (int k = 0; k < 33; k++) {
        int a = tid + k * 256;
        unsigned long long kk = 0ull;
        if (a < NA) {
            unsigned int fb = __float_as_uint(mtr[a]);   // values >= 0
            kk = ((unsigned long long)fb << 32) | (unsigned int)(~a);
        }
        key[k] = kk;
    }
    __shared__ unsigned long long red[256];
    __shared__ int sel[TOPK];
    for (int it = 0; it < TOPK; it++) {
        unsigned long long m = 0ull;
#pragma unroll
        for (int k = 0; k < 33; k++) m = (key[k] > m) ? key[k] : m;
        red[tid] = m;
        __syncthreads();
        for (int s = 128; s > 0; s >>= 1) {
            if (tid < s) {
                unsigned long long o = red[tid + s];
                if (o > red[tid]) red[tid] = o;
            }
            __syncthreads();
        }
        unsigned long long win = red[0];
        if (tid == 0) sel[it] = (int)(~(unsigned int)win);
#pragma unroll
        for (int k = 0; k < 33; k++)
            if (key[k] == win) key[k] = 0ull;
        __syncthreads();
    }
    if (tid < TOPK) {
        int a = sel[tid];
        const float* gb = gt_box + (size_t)row * 4;
        float ax = anchors[a * 2], ay = anchors[a * 2 + 1];
        float dmin = fminf(fminf(ax - gb[0], ay - gb[1]),
                           fminf(gb[2] - ax, gb[3] - ay));
        if (dmin > EPS9) mp[a] = 1;   // count * mask_in_gts * mask
    }
}

// ---------------- kernel 3: per-anchor resolve ----------------
__global__ __launch_bounds__(256) void k3_resolve(
    const float* __restrict__ overlaps,
    unsigned char* __restrict__ mask_pos,
    const float* __restrict__ gt_box,
    int* __restrict__ gt_idx,               // (BS,NA)
    unsigned char* __restrict__ fg_arr,     // (BS,NA)
    float* __restrict__ out_bbox,           // (BS,NA,4)
    float* __restrict__ out_fg)             // (BS,NA)
{
    int i = blockIdx.x * 256 + threadIdx.x;
    if (i >= BS * NA) return;
    int b = i / NA, a = i % NA;
    const float* ov = overlaps + (size_t)b * NMAX * NA + a;
    unsigned char* mp = mask_pos + (size_t)b * NMAX * NA + a;

    int fg0 = 0, first = -1, argn = 0;
    float best = ov[0];
    for (int n = 0; n < NMAX; n++) {
        unsigned char m = mp[(size_t)n * NA];
        fg0 += m;
        if (m && first < 0) first = n;
        if (n > 0) {
            float v = ov[(size_t)n * NA];
            if (v > best) { best = v; argn = n; }
        }
    }
    int gi, fg;
    if (fg0 > 1) {
        for (int n = 0; n < NMAX; n++)
            mp[(size_t)n * NA] = (n == argn) ? 1 : 0;
        gi = argn; fg = 1;
    } else {
        gi = (first >= 0) ? first : 0;
        fg = fg0;
    }
    gt_idx[i] = gi;
    fg_arr[i] = (unsigned char)fg;
    out_fg[i] = fg ? 1.0f : 0.0f;
    const float* gb = gt_box + ((size_t)b * NMAX + gi) * 4;
    out_bbox[(size_t)i * 4 + 0] = gb[0];
    out_bbox[(size_t)i * 4 + 1] = gb[1];
    out_bbox[(size_t)i * 4 + 2] = gb[2];
    out_bbox[(size_t)i * 4 + 3] = gb[3];
}

// ---------------- kernel 4: per-row maxima with final mask ----------------
__global__ __launch_bounds__(256) void k4_rowmax(
    const float* __restrict__ metric,
    const float* __restrict__ overlaps,
    const unsigned char* __restrict__ mask_pos,
    float* __restrict__ pos_metrics,    // (BS*NMAX)
    float* __restrict__ pos_overlaps)   // (BS*NMAX)
{
    int row = blockIdx.x;
    int tid = threadIdx.x;
    const float* mtr = metric + (size_t)row * NA;
    const float* ovr = overlaps + (size_t)row * NA;
    const unsigned char* mp = mask_pos + (size_t)row * NA;
    float mm = 0.f, mo = 0.f;
    for (int a = tid; a < NA; a += 256) {
        if (mp[a]) {
            mm = fmaxf(mm, mtr[a]);
            mo = fmaxf(mo, ovr[a]);
        }
    }
    __shared__ float sm[256], so[256];
    sm[tid] = mm; so[tid] = mo;
    __syncthreads();
    for (int s = 128; s > 0; s >>= 1) {
        if (tid < s) {
            sm[tid] = fmaxf(sm[tid], sm[tid + s]);
            so[tid] = fmaxf(so[tid], so[tid + s]);
        }
        __syncthreads();
    }
    if (tid == 0) {
        pos_metrics[row]  = sm[0];
        pos_overlaps[row] = so[0];
    }
}

// ---------------- kernel 5: target_scores write-out ----------------
__global__ __launch_bounds__(256) void k5_scores(
    const float* __restrict__ metric,
    const int*   __restrict__ gt_idx,
    const unsigned char* __restrict__ fg_arr,
    const int*   __restrict__ gt_labels,
    const float* __restrict__ pos_metrics,
    const float* __restrict__ pos_overlaps,
    float* __restrict__ out_scores)         // (BS,NA,NCLS)
{
    int i = blockIdx.x * 256 + threadIdx.x;
    if (i >= BS * NA * NCLS) return;
    int c  = i % NCLS;
    int ba = i / NCLS;
    float val = 0.f;
    if (fg_arr[ba]) {
        int b = ba / NA, a = ba % NA;
        int gi = gt_idx[ba];
        int lbl = gt_labels[b * NMAX + gi];
        if (lbl < 0) lbl = 0;
        if (c == lbl) {
            int row = b * NMAX + gi;
            float m = metric[(size_t)row * NA + a];
            val = m * pos_overlaps[row] / (pos_metrics[row] + 1e-9f);
        }
    }
    out_scores[i] = val;
}

extern "C" void kernel_launch(void* const* d_in, const int* in_sizes, int n_in,
                              void* d_out, int out_size, void* d_ws, size_t ws_size,
                              hipStream_t stream) {
    (void)in_sizes; (void)n_in; (void)out_size; (void)ws_size;
    const float* score     = (const float*)d_in[0];
    const float* p_box     = (const float*)d_in[1];
    const float* anchors   = (const float*)d_in[2];
    const int*   gt_labels = (const int*)d_in[3];
    const float* gt_box    = (const float*)d_in[4];
    const float* mask      = (const float*)d_in[5];

    // workspace layout
    const size_t plane = (size_t)BS * NMAX * NA;            // 8,601,600
    float* overlaps = (float*)d_ws;
    float* metric   = overlaps + plane;
    unsigned char* mask_pos = (unsigned char*)(metric + plane);
    int* gt_idx = (int*)(mask_pos + plane);                 // plane bytes, 4-aligned
    unsigned char* fg_arr = (unsigned char*)(gt_idx + (size_t)BS * NA);
    float* pos_metrics  = (float*)(fg_arr + ((size_t)BS * NA + 3) / 4 * 4);
    float* pos_overlaps = pos_metrics + (size_t)BS * NMAX;

    float* out_bbox   = (float*)d_out;                      // BS*NA*4
    float* out_scores = out_bbox + (size_t)BS * NA * 4;     // BS*NA*NCLS
    float* out_fg     = out_scores + (size_t)BS * NA * NCLS;// BS*NA

    const int ROWS = BS * NMAX;    // 1024
    hipLaunchKernelGGL(k1_compute, dim3(ROWS), dim3(256), 0, stream,
                       score, p_box, anchors, gt_labels, gt_box, mask,
                       overlaps, metric);
    hipLaunchKernelGGL(k2_topk, dim3(ROWS), dim3(256), 0, stream,
                       metric, anchors, gt_box, mask, mask_pos);
    hipLaunchKernelGGL(k3_resolve, dim3((BS * NA + 255) / 256), dim3(256), 0, stream,
                       overlaps, mask_pos, gt_box, gt_idx, fg_arr, out_bbox, out_fg);
    hipLaunchKernelGGL(k4_rowmax, dim3(ROWS), dim3(256), 0, stream,
                       metric, overlaps, mask_pos, pos_metrics, pos_overlaps);
    hipLaunchKernelGGL(k5_scores, dim3((BS * NA * NCLS + 255) / 256), dim3(256), 0, stream,
                       metric, gt_idx, fg_arr, gt_labels,
                       pos_metrics, pos_overlaps, out_scores);
}

// Round 2
// 173.312 us; speedup vs baseline: 1.1281x; 1.1281x over previous
//
#include <hip/hip_runtime.h>
#include <math.h>

#define BS   16
#define NMAX 64
#define NA   8400
#define NCLS 80
#define TOPK 10
#define NTH  512
#define KPT  17              // ceil(NA/NTH)
#define NWAVE (NTH/64)

typedef unsigned long long u64;

// ---- k1: compute overlaps/metric + in-register top-k -> bitmask ----
__global__ __launch_bounds__(NTH) void k1_fused(
    const float* __restrict__ score,    // (BS,NA,NCLS)
    const float* __restrict__ p_box,    // (BS,NA,4)
    const float* __restrict__ anchors,  // (NA,2)
    const int*   __restrict__ gt_labels,// (BS,NMAX)
    const float* __restrict__ gt_box,   // (BS,NMAX,4)
    const float* __restrict__ mask,     // (BS,NMAX)
    float* __restrict__ overlaps,       // (BS*NMAX, NA)
    float* __restrict__ metric,         // (BS*NMAX, NA)
    u64*   __restrict__ mask64)         // (BS, NA)
{
    int row = blockIdx.x;               // b*NMAX + n
    if (mask[row] <= 0.f) return;       // invalid rows: nothing read downstream
    int b = row >> 6;
    int n = row & 63;
    const float* gb = gt_box + (size_t)row * 4;
    float gx1 = gb[0], gy1 = gb[1], gx2 = gb[2], gy2 = gb[3];
    int lbl = gt_labels[row];
    float w1 = gx2 - gx1;
    float h1 = gy2 - gy1 + 1e-7f;
    float at1 = atanf(w1 / h1);
    float area1 = w1 * h1;

    float* ovr = overlaps + (size_t)row * NA;
    float* mtr = metric   + (size_t)row * NA;
    const float* sc = score + (size_t)b * NA * NCLS + lbl;
    const float* pb = p_box + (size_t)b * NA * 4;

    int tid = threadIdx.x;
    u64 key[KPT];
#pragma unroll
    for (int k = 0; k < KPT; k++) {
        int a = tid + k * NTH;
        u64 kk = 0ull;
        if (a < NA) {
            float ov = 0.f, mt = 0.f;
            float ax = anchors[a * 2], ay = anchors[a * 2 + 1];
            float dmin = fminf(fminf(ax - gx1, ay - gy1), fminf(gx2 - ax, gy2 - ay));
            if (dmin > 1e-9f) {
                float px1 = pb[a*4], py1 = pb[a*4+1], px2 = pb[a*4+2], py2 = pb[a*4+3];
                float w2 = px2 - px1;
                float h2 = py2 - py1 + 1e-7f;
                float iw = fminf(gx2, px2) - fmaxf(gx1, px1);
                float ih = fminf(gy2, py2) - fmaxf(gy1, py1);
                float inter = fmaxf(iw, 0.f) * fmaxf(ih, 0.f);
                float uni = area1 + w2 * h2 - inter + 1e-7f;
                float iou = inter / uni;
                float cw = fmaxf(gx2, px2) - fminf(gx1, px1);
                float ch = fmaxf(gy2, py2) - fminf(gy1, py1);
                float c2 = cw * cw + ch * ch + 1e-7f;
                float dx = (px1 + px2 - gx1 - gx2);
                float dy = (py1 + py2 - gy1 - gy2);
                float rho2 = (dx * dx + dy * dy) * 0.25f;
                float dat = atanf(w2 / h2) - at1;
                float v = (4.0f / (float)(M_PI * M_PI)) * dat * dat;
                float alpha = v / (v - iou + (1.0f + 1e-7f));
                float ciou = iou - (rho2 / c2 + v * alpha);
                ov = fmaxf(ciou, 0.f);
                float gath = sc[(size_t)a * NCLS];
                float ov2 = ov * ov;
                mt = sqrtf(gath) * ov2 * ov2 * ov2;    // gath^0.5 * ov^6
            }
            ovr[a] = ov;
            mtr[a] = mt;
            kk = ((u64)__float_as_uint(mt) << 32) | (unsigned)(~a);
        }
        key[k] = kk;
    }

    // top-10: iterative block-max with removal; key packs (val, ~idx) -> total
    // order matching lax.top_k (value desc, index asc on ties)
    __shared__ u64 wred[NWAVE];
    __shared__ u64 swin_s;
    __shared__ int sel[TOPK];
    for (int it = 0; it < TOPK; it++) {
        u64 m = 0ull;
#pragma unroll
        for (int k = 0; k < KPT; k++) m = (key[k] > m) ? key[k] : m;
#pragma unroll
        for (int off = 32; off > 0; off >>= 1) {
            u64 o = __shfl_xor(m, off);
            if (o > m) m = o;
        }
        if ((tid & 63) == 0) wred[tid >> 6] = m;
        __syncthreads();
        if (tid == 0) {
            u64 w = wred[0];
#pragma unroll
            for (int j = 1; j < NWAVE; j++) if (wred[j] > w) w = wred[j];
            swin_s = w;
            sel[it] = (int)(~(unsigned)(w & 0xffffffffu));
        }
        __syncthreads();
        u64 win = swin_s;
#pragma unroll
        for (int k = 0; k < KPT; k++) if (key[k] == win) key[k] = 0ull;
    }
    if (tid < TOPK) {
        int a = sel[tid];
        float ax = anchors[a * 2], ay = anchors[a * 2 + 1];
        float dmin = fminf(fminf(ax - gx1, ay - gy1), fminf(gx2 - ax, gy2 - ay));
        if (dmin > 1e-9f)                          // count * mask_in_gts * mask
            atomicOr(&mask64[(size_t)b * NA + a], 1ull << n);
    }
}

// ---- k3: per-anchor resolve from bitmask; pos maxima via atomicMax ----
__global__ __launch_bounds__(256) void k3_resolve(
    const float* __restrict__ overlaps,
    const float* __restrict__ metric,
    const u64*   __restrict__ mask64,
    const float* __restrict__ mask,
    const float* __restrict__ gt_box,
    int* __restrict__ gt_idx,
    unsigned char* __restrict__ fg_arr,
    float* __restrict__ out_bbox,
    float* __restrict__ out_fg,
    float* __restrict__ pos_metrics,     // int-atomicMax on float bits (>=0)
    float* __restrict__ pos_overlaps)
{
    int i = blockIdx.x * 256 + threadIdx.x;
    if (i >= BS * NA) return;
    int b = i / NA, a = i - b * NA;
    u64 bits = mask64[i];
    int fg0 = __popcll(bits);
    int gi, fg;
    if (fg0 > 1) {
        // first-max argmax over masked overlaps column (invalid rows are 0)
        const float* ov = overlaps + (size_t)b * NMAX * NA + a;
        const float* mrow = mask + b * NMAX;
        float best = -1.f; int argn = 0;
        for (int nn = 0; nn < NMAX; nn++) {
            float v = (mrow[nn] > 0.f) ? ov[(size_t)nn * NA] : 0.f;
            if (v > best) { best = v; argn = nn; }
        }
        gi = argn; fg = 1;
    } else {
        gi = fg0 ? (__ffsll(bits) - 1) : 0;
        fg = fg0;
    }
    gt_idx[i] = gi;
    fg_arr[i] = (unsigned char)fg;
    out_fg[i] = fg ? 1.f : 0.f;
    int r = b * NMAX + gi;
    float4 bb = *(const float4*)(gt_box + (size_t)r * 4);
    ((float4*)out_bbox)[i] = bb;
    if (fg) {
        float m = metric[(size_t)r * NA + a];
        float o = overlaps[(size_t)r * NA + a];
        atomicMax((int*)&pos_metrics[r],  __float_as_int(m));
        atomicMax((int*)&pos_overlaps[r], __float_as_int(o));
    }
}

// ---- k5: sparse score write (rest pre-zeroed by memset) ----
__global__ __launch_bounds__(256) void k5_sparse(
    const float* __restrict__ metric,
    const int*   __restrict__ gt_idx,
    const unsigned char* __restrict__ fg_arr,
    const int*   __restrict__ gt_labels,
    const float* __restrict__ pos_metrics,
    const float* __restrict__ pos_overlaps,
    float* __restrict__ out_scores)
{
    int i = blockIdx.x * 256 + threadIdx.x;
    if (i >= BS * NA) return;
    if (!fg_arr[i]) return;
    int b = i / NA, a = i - b * NA;
    int r = b * NMAX + gt_idx[i];
    int lbl = gt_labels[r]; if (lbl < 0) lbl = 0;
    float m = metric[(size_t)r * NA + a];
    float val = m * pos_overlaps[r] / (pos_metrics[r] + 1e-9f);
    out_scores[(size_t)i * NCLS + lbl] = val;
}

extern "C" void kernel_launch(void* const* d_in, const int* in_sizes, int n_in,
                              void* d_out, int out_size, void* d_ws, size_t ws_size,
                              hipStream_t stream) {
    (void)in_sizes; (void)n_in; (void)out_size; (void)ws_size;
    const float* score     = (const float*)d_in[0];
    const float* p_box     = (const float*)d_in[1];
    const float* anchors   = (const float*)d_in[2];
    const int*   gt_labels = (const int*)d_in[3];
    const float* gt_box    = (const float*)d_in[4];
    const float* mask      = (const float*)d_in[5];

    const size_t plane = (size_t)BS * NMAX * NA;      // 8,601,600
    float* overlaps = (float*)d_ws;
    float* metric   = overlaps + plane;
    u64*   mask64   = (u64*)(metric + plane);         // offset 68812800, 8-aligned
    int*   gt_idx   = (int*)(mask64 + (size_t)BS * NA);
    unsigned char* fg_arr = (unsigned char*)(gt_idx + (size_t)BS * NA);
    float* pos_metrics  = (float*)(fg_arr + (((size_t)BS * NA + 7) / 8) * 8);
    float* pos_overlaps = pos_metrics + (size_t)BS * NMAX;

    float* out_bbox   = (float*)d_out;                      // BS*NA*4
    float* out_scores = out_bbox + (size_t)BS * NA * 4;     // BS*NA*NCLS
    float* out_fg     = out_scores + (size_t)BS * NA * NCLS;// BS*NA

    hipMemsetAsync(mask64, 0, (size_t)BS * NA * sizeof(u64), stream);
    hipMemsetAsync(pos_metrics, 0, 2 * (size_t)BS * NMAX * sizeof(float), stream);
    hipMemsetAsync(out_scores, 0, (size_t)BS * NA * NCLS * sizeof(float), stream);

    hipLaunchKernelGGL(k1_fused, dim3(BS * NMAX), dim3(NTH), 0, stream,
                       score, p_box, anchors, gt_labels, gt_box, mask,
                       overlaps, metric, mask64);
    hipLaunchKernelGGL(k3_resolve, dim3((BS * NA + 255) / 256), dim3(256), 0, stream,
                       overlaps, metric, mask64, mask, gt_box,
                       gt_idx, fg_arr, out_bbox, out_fg, pos_metrics, pos_overlaps);
    hipLaunchKernelGGL(k5_sparse, dim3((BS * NA + 255) / 256), dim3(256), 0, stream,
                       metric, gt_idx, fg_arr, gt_labels,
                       pos_metrics, pos_overlaps, out_scores);
}